// Round 7
// baseline (144.996 us; speedup 1.0000x reference)
//
#include <hip/hip_runtime.h>
#include <cstdint>

// Problem constants: N=8192, T=1024, CD=4, H=2, KD=VD=8, DA=8, AOD=16, LAT=64, OUT=32.
//
// R6 established: split phases => no spill (WRITE=512KB, VGPR=52). Phase1 is
// latency-bound (VALUBusy 20%, HBM 7%, inputs L3-resident). R7: deepen the
// load pipeline with double-buffered chunks of 4 (~8 VMEM in flight). VGPR
// budget up to ~96 is free (LDS 32KB caps occupancy at 5 blocks/CU anyway).

__device__ __forceinline__ float bflo(uint32_t u) { return __uint_as_float(u << 16); }
__device__ __forceinline__ float bfhi(uint32_t u) { return __uint_as_float(u & 0xFFFF0000u); }
__device__ __forceinline__ uint32_t f2bf(float f) {
    uint32_t x = __float_as_uint(f);
    return (x + 0x7FFFu + ((x >> 16) & 1u)) >> 16;   // RNE
}
__device__ __forceinline__ float ftanh(float x) {
    float e = __expf(2.0f * x);
    return 1.0f - 2.0f / (e + 1.0f);   // stable for +-inf of e
}

// ---------------- phase 1: masked attention -> attn[n,16] ----------------
__global__ void attn_phase1(const float* __restrict__ coord1,
                            const float* __restrict__ att_coeff,
                            const float* __restrict__ local_coords,
                            const void*  __restrict__ maskp,
                            const float* __restrict__ Wq, const float* __restrict__ Bq,
                            const float* __restrict__ Wk, const float* __restrict__ Bk,
                            const float* __restrict__ Wv, const float* __restrict__ Bv,
                            float* __restrict__ ws)
{
    __shared__ uint4 vq[2048];                 // v table, bf16x2 packed, swizzled (32 KB)

    const int tid  = threadIdx.x;
    const int lane = tid & 63;
    const int wid  = tid >> 6;

    // mask element size: 4-byte (int/float 0/1) vs 1-byte (bool)
    uint4 mm = ((const uint4*)maskp)[tid];
    bool ok = (mm.x <= 1u || mm.x == 0x3F800000u) &&
              (mm.y <= 1u || mm.y == 0x3F800000u) &&
              (mm.z <= 1u || mm.z == 0x3F800000u) &&
              (mm.w <= 1u || mm.w == 0x3F800000u);
    const bool m4 = (__all(ok) != 0);

    // stage v = att_coeff @ Wv + Bv (bf16x2, XOR-swizzled)
    #pragma unroll
    for (int tt = 0; tt < 4; ++tt) {
        const int t = tid * 4 + tt;
        const float4 a0 = *(const float4*)(att_coeff + t * 8);
        const float4 a1 = *(const float4*)(att_coeff + t * 8 + 4);
        float vr[16];
        #pragma unroll
        for (int o = 0; o < 16; ++o) {
            vr[o] = Bv[o]
                + a0.x * Wv[o]      + a0.y * Wv[16 + o] + a0.z * Wv[32 + o] + a0.w * Wv[48 + o]
                + a1.x * Wv[64 + o] + a1.y * Wv[80 + o] + a1.z * Wv[96 + o] + a1.w * Wv[112 + o];
        }
        #pragma unroll
        for (int h = 0; h < 2; ++h) {
            const int g  = 2 * t + h;
            const int gs = (g & ~7) | ((g ^ (g >> 3)) & 7);
            uint4 pk;
            pk.x = f2bf(vr[h * 8 + 0]) | (f2bf(vr[h * 8 + 1]) << 16);
            pk.y = f2bf(vr[h * 8 + 2]) | (f2bf(vr[h * 8 + 3]) << 16);
            pk.z = f2bf(vr[h * 8 + 4]) | (f2bf(vr[h * 8 + 5]) << 16);
            pk.w = f2bf(vr[h * 8 + 6]) | (f2bf(vr[h * 8 + 7]) << 16);
            vq[gs] = pk;
        }
    }
    __syncthreads();

    const int l  = lane & 31;          // t-slot within half-wave
    const int hb = (lane >> 5) * 8;    // own head base (0 or 8)
    const int g0 = 2 * l + (lane >> 5);
    const int bg = (g0 & ~7) | ((g0 ^ (g0 >> 3)) & 7);   // vq[bg + 64*i]
    const float rs8 = 0.35355339059327373f;              // 1/sqrt(KD)

    const uint32_t msh   = m4 ? 0u : ((l & 3) * 8);
    const uint32_t mmsk  = m4 ? 0xFFFFFFFFu : 0xFFu;
    const int      mstep = m4 ? 32 : 8;

    const int n = (blockIdx.x << 2) + wid;     // one row per wave

    // own-head q -> folded A[4], Bs (q dead after)
    float A0, A1, A2, A3, Bsv;
    {
        const float4 c1 = *(const float4*)(coord1 + n * 4);
        float qd[8];
        #pragma unroll
        for (int d = 0; d < 8; ++d)
            qd[d] = Bq[hb + d]
                  + c1.x * Wq[0 * 16 + hb + d] + c1.y * Wq[1 * 16 + hb + d]
                  + c1.z * Wq[2 * 16 + hb + d] + c1.w * Wq[3 * 16 + hb + d];
        float a[4];
        #pragma unroll
        for (int c = 0; c < 4; ++c) {
            float s = 0.f;
            #pragma unroll
            for (int d = 0; d < 8; ++d) s += qd[d] * Wk[c * 16 + hb + d];
            a[c] = s * rs8;
        }
        float s2 = 0.f;
        #pragma unroll
        for (int d = 0; d < 8; ++d) s2 += qd[d] * Bk[hb + d];
        A0 = a[0]; A1 = a[1]; A2 = a[2]; A3 = a[3]; Bsv = s2 * rs8;
    }

    // stream own head's T-slice: t = l + 32*i, double-buffered chunks of 4
    const float4*   lcp = (const float4*)local_coords + (size_t)n * 1024 + l;
    const uint32_t* mp  = (const uint32_t*)maskp +
                          (m4 ? ((size_t)n * 1024 + l)
                              : ((size_t)n * 256 + (l >> 2)));

    float p0 = 0.f, p1 = 0.f, p2 = 0.f, p3 = 0.f;
    float p4 = 0.f, p5 = 0.f, p6 = 0.f, p7 = 0.f;
    float s0 = 0.f;

    float4   lA[4], lB[4];
    uint32_t mA[4], mB[4];

#define LOADC(LBUF, MBUF, CB)                                             \
    {                                                                     \
        _Pragma("unroll")                                                 \
        for (int j = 0; j < 4; ++j) {                                     \
            LBUF[j] = lcp[((CB) * 4 + j) * 32];                           \
            MBUF[j] = mp[((CB) * 4 + j) * mstep];                         \
        }                                                                 \
    }

#define COMPC(LBUF, MBUF, CB)                                             \
    {                                                                     \
        _Pragma("unroll")                                                 \
        for (int j = 0; j < 4; ++j) {                                     \
            const bool keep = ((MBUF[j] >> msh) & mmsk) != 0u;            \
            const float v = Bsv + LBUF[j].x * A0 + LBUF[j].y * A1         \
                                + LBUF[j].z * A2 + LBUF[j].w * A3;        \
            const float e = keep ? __expf(v) : 0.f;                       \
            s0 += e;                                                      \
            const uint4 w = vq[bg + (((CB) * 4 + j) << 6)];               \
            p0 += e * bflo(w.x); p1 += e * bfhi(w.x);                     \
            p2 += e * bflo(w.y); p3 += e * bfhi(w.y);                     \
            p4 += e * bflo(w.z); p5 += e * bfhi(w.z);                     \
            p6 += e * bflo(w.w); p7 += e * bfhi(w.w);                     \
        }                                                                 \
    }

    LOADC(lA, mA, 0);
    LOADC(lB, mB, 1);  COMPC(lA, mA, 0);
    LOADC(lA, mA, 2);  COMPC(lB, mB, 1);
    LOADC(lB, mB, 3);  COMPC(lA, mA, 2);
    LOADC(lA, mA, 4);  COMPC(lB, mB, 3);
    LOADC(lB, mB, 5);  COMPC(lA, mA, 4);
    LOADC(lA, mA, 6);  COMPC(lB, mB, 5);
    LOADC(lB, mB, 7);  COMPC(lA, mA, 6);
                       COMPC(lB, mB, 7);
#undef LOADC
#undef COMPC

    // head-total sum across the half-wave
    #pragma unroll
    for (int s = 16; s; s >>= 1) s0 += __shfl_xor(s0, s, 64);

    // all-masked fallback: softmax of constant row = uniform weights
    if (s0 == 0.0f) {
        #pragma unroll 2
        for (int i = 0; i < 32; ++i) {
            const uint4 w = vq[bg + (i << 6)];
            p0 += bflo(w.x); p1 += bfhi(w.x);
            p2 += bflo(w.y); p3 += bfhi(w.y);
            p4 += bflo(w.z); p5 += bfhi(w.z);
            p6 += bflo(w.w); p7 += bfhi(w.w);
        }
        s0 = 1024.0f;
    }

    // split butterfly within half-wave: lane ends with elem (lane>>2)&7
    {
        const bool b = (lane & 16) != 0;
        const float n0 = (b ? p4 : p0) + __shfl_xor(b ? p0 : p4, 16, 64);
        const float n1 = (b ? p5 : p1) + __shfl_xor(b ? p1 : p5, 16, 64);
        const float n2 = (b ? p6 : p2) + __shfl_xor(b ? p2 : p6, 16, 64);
        const float n3 = (b ? p7 : p3) + __shfl_xor(b ? p3 : p7, 16, 64);
        p0 = n0; p1 = n1; p2 = n2; p3 = n3;
    }
    {
        const bool b = (lane & 8) != 0;
        const float n0 = (b ? p2 : p0) + __shfl_xor(b ? p0 : p2, 8, 64);
        const float n1 = (b ? p3 : p1) + __shfl_xor(b ? p1 : p3, 8, 64);
        p0 = n0; p1 = n1;
    }
    {
        const bool b = (lane & 4) != 0;
        p0 = (b ? p1 : p0) + __shfl_xor(b ? p0 : p1, 4, 64);
    }
    p0 += __shfl_xor(p0, 2, 64);
    p0 += __shfl_xor(p0, 1, 64);

    if ((lane & 3) == 0)
        ws[(size_t)n * 16 + hb + ((lane >> 2) & 7)] = p0 / s0;
}

// ---------------- phase 2: Wo/exp + tanh MLP ----------------
__global__ void attn_phase2(const float* __restrict__ coord1,
                            const float* __restrict__ coord2,
                            const float* __restrict__ ws,
                            const float* __restrict__ Wo, const float* __restrict__ Bo,
                            const float* __restrict__ W1, const float* __restrict__ B1,
                            const float* __restrict__ W2, const float* __restrict__ B2,
                            const float* __restrict__ Wt, const float* __restrict__ Bt,
                            float* __restrict__ out)
{
    const int lane = threadIdx.x & 63;
    const int wid  = threadIdx.x >> 6;
    const int n    = (blockIdx.x << 2) + wid;  // one row per wave

    const float4 c1 = *(const float4*)(coord1 + n * 4);
    const float4 c2 = *(const float4*)(coord2 + n * 4);
    const float  av = ws[(size_t)n * 16 + (lane & 15)];   // lane c<16 holds attn[c]

    // att[j] = exp(-(attn . Wo[:,j] + Bo[j])), j = lane&15
    float attv;
    {
        const int j = lane & 15;
        float acc = Bo[j];
        #pragma unroll
        for (int c = 0; c < 16; ++c)
            acc += __shfl(av, c, 64) * Wo[c * 16 + j];
        attv = __expf(-acc);
    }

    // layer 1: act1[lane] = tanh([c1,c2,att] . W1[:,lane] + B1[lane])
    float a1;
    {
        float acc = B1[lane];
        acc += c1.x * W1[0 * 64 + lane] + c1.y * W1[1 * 64 + lane]
             + c1.z * W1[2 * 64 + lane] + c1.w * W1[3 * 64 + lane];
        acc += c2.x * W1[4 * 64 + lane] + c2.y * W1[5 * 64 + lane]
             + c2.z * W1[6 * 64 + lane] + c2.w * W1[7 * 64 + lane];
        #pragma unroll
        for (int c = 0; c < 16; ++c)
            acc += __shfl(attv, c, 64) * W1[(8 + c) * 64 + lane];
        a1 = ftanh(acc);
    }

    // layer 2: act2[lane] = tanh(act1 . W2[:,lane] + B2[lane])
    float a2;
    {
        float acc = B2[lane];
        #pragma unroll
        for (int c = 0; c < 64; ++c)
            acc += __shfl(a1, c, 64) * W2[c * 64 + lane];
        a2 = ftanh(acc);
    }

    // layer 3: out[lane&31] = tanh(act2 . Wt[:,lane&31] + Bt[lane&31])
    {
        const int j = lane & 31;
        float acc = Bt[j];
        #pragma unroll
        for (int c = 0; c < 64; ++c)
            acc += __shfl(a2, c, 64) * Wt[c * 32 + j];
        if (lane < 32) out[(size_t)n * 32 + lane] = ftanh(acc);
    }
}

extern "C" void kernel_launch(void* const* d_in, const int* in_sizes, int n_in,
                              void* d_out, int out_size, void* d_ws, size_t ws_size,
                              hipStream_t stream) {
    (void)in_sizes; (void)n_in; (void)out_size; (void)ws_size;
    float* ws = (float*)d_ws;   // 8192*16 floats = 512 KB
    attn_phase1<<<2048, 256, 0, stream>>>(
        (const float*)d_in[0],  (const float*)d_in[2],
        (const float*)d_in[3],  d_in[4],
        (const float*)d_in[5],  (const float*)d_in[6],
        (const float*)d_in[7],  (const float*)d_in[8],
        (const float*)d_in[9],  (const float*)d_in[10],
        ws);
    attn_phase2<<<2048, 256, 0, stream>>>(
        (const float*)d_in[0],  (const float*)d_in[1],
        ws,
        (const float*)d_in[11], (const float*)d_in[12],
        (const float*)d_in[13], (const float*)d_in[14],
        (const float*)d_in[15], (const float*)d_in[16],
        (const float*)d_in[17], (const float*)d_in[18],
        (float*)d_out);
}

// Round 8
// 83.036 us; speedup vs baseline: 1.7462x; 1.7462x over previous
//
#include <hip/hip_runtime.h>
#include <cstdint>

// Problem constants: N=8192, T=1024, CD=4, H=2, KD=VD=8, DA=8, AOD=16, LAT=64, OUT=32.
//
// Established (R1-R7): allocator caps these kernels at 64 VGPR and spills
// anything past it (R7: 8xfloat4 dbuf -> 185MB scratch writes). So ILP-deep
// register pipelines are OFF the table. R6 (52 VGPR, no spill) is the best
// inner loop. R8 lever: OCCUPANCY. 512-thread blocks share one 32KB v-table
// -> LDS/wave halves -> 4 blocks x 8 waves = 32 waves/CU (100%), whole grid
// resident. Inner loop identical to R6.

__device__ __forceinline__ float bflo(uint32_t u) { return __uint_as_float(u << 16); }
__device__ __forceinline__ float bfhi(uint32_t u) { return __uint_as_float(u & 0xFFFF0000u); }
__device__ __forceinline__ uint32_t f2bf(float f) {
    uint32_t x = __float_as_uint(f);
    return (x + 0x7FFFu + ((x >> 16) & 1u)) >> 16;   // RNE
}
__device__ __forceinline__ float ftanh(float x) {
    float e = __expf(2.0f * x);
    return 1.0f - 2.0f / (e + 1.0f);   // stable for +-inf of e
}

// ---------------- phase 1: masked attention -> attn[n,16] ----------------
__global__ __launch_bounds__(512)
void attn_phase1(const float* __restrict__ coord1,
                 const float* __restrict__ att_coeff,
                 const float* __restrict__ local_coords,
                 const void*  __restrict__ maskp,
                 const float* __restrict__ Wq, const float* __restrict__ Bq,
                 const float* __restrict__ Wk, const float* __restrict__ Bk,
                 const float* __restrict__ Wv, const float* __restrict__ Bv,
                 float* __restrict__ ws)
{
    __shared__ uint4 vq[2048];                 // v table, bf16x2 packed, swizzled (32 KB, 8 waves share)

    const int tid  = threadIdx.x;
    const int lane = tid & 63;
    const int wid  = tid >> 6;                 // 0..7

    // mask element size: 4-byte (int/float 0/1) vs 1-byte (bool)
    uint4 mm = ((const uint4*)maskp)[tid];
    bool ok = (mm.x <= 1u || mm.x == 0x3F800000u) &&
              (mm.y <= 1u || mm.y == 0x3F800000u) &&
              (mm.z <= 1u || mm.z == 0x3F800000u) &&
              (mm.w <= 1u || mm.w == 0x3F800000u);
    const bool m4 = (__all(ok) != 0);

    // stage v = att_coeff @ Wv + Bv (bf16x2, XOR-swizzled); 2 t's per thread
    #pragma unroll
    for (int tt = 0; tt < 2; ++tt) {
        const int t = tid * 2 + tt;
        const float4 a0 = *(const float4*)(att_coeff + t * 8);
        const float4 a1 = *(const float4*)(att_coeff + t * 8 + 4);
        float vr[16];
        #pragma unroll
        for (int o = 0; o < 16; ++o) {
            vr[o] = Bv[o]
                + a0.x * Wv[o]      + a0.y * Wv[16 + o] + a0.z * Wv[32 + o] + a0.w * Wv[48 + o]
                + a1.x * Wv[64 + o] + a1.y * Wv[80 + o] + a1.z * Wv[96 + o] + a1.w * Wv[112 + o];
        }
        #pragma unroll
        for (int h = 0; h < 2; ++h) {
            const int g  = 2 * t + h;
            const int gs = (g & ~7) | ((g ^ (g >> 3)) & 7);
            uint4 pk;
            pk.x = f2bf(vr[h * 8 + 0]) | (f2bf(vr[h * 8 + 1]) << 16);
            pk.y = f2bf(vr[h * 8 + 2]) | (f2bf(vr[h * 8 + 3]) << 16);
            pk.z = f2bf(vr[h * 8 + 4]) | (f2bf(vr[h * 8 + 5]) << 16);
            pk.w = f2bf(vr[h * 8 + 6]) | (f2bf(vr[h * 8 + 7]) << 16);
            vq[gs] = pk;
        }
    }
    __syncthreads();

    const int l  = lane & 31;          // t-slot within half-wave
    const int hb = (lane >> 5) * 8;    // own head base (0 or 8)
    const int g0 = 2 * l + (lane >> 5);
    const int bg = (g0 & ~7) | ((g0 ^ (g0 >> 3)) & 7);   // vq[bg + 64*i]
    const float rs8 = 0.35355339059327373f;              // 1/sqrt(KD)

    const uint32_t msh   = m4 ? 0u : ((l & 3) * 8);
    const uint32_t mmsk  = m4 ? 0xFFFFFFFFu : 0xFFu;
    const int      mstep = m4 ? 32 : 8;

    const int n = (blockIdx.x << 3) + wid;     // one row per wave, 8 rows/block

    // own-head q -> folded A[4], Bs (q dead after)
    float A0, A1, A2, A3, Bsv;
    {
        const float4 c1 = *(const float4*)(coord1 + n * 4);
        float qd[8];
        #pragma unroll
        for (int d = 0; d < 8; ++d)
            qd[d] = Bq[hb + d]
                  + c1.x * Wq[0 * 16 + hb + d] + c1.y * Wq[1 * 16 + hb + d]
                  + c1.z * Wq[2 * 16 + hb + d] + c1.w * Wq[3 * 16 + hb + d];
        float a[4];
        #pragma unroll
        for (int c = 0; c < 4; ++c) {
            float s = 0.f;
            #pragma unroll
            for (int d = 0; d < 8; ++d) s += qd[d] * Wk[c * 16 + hb + d];
            a[c] = s * rs8;
        }
        float s2 = 0.f;
        #pragma unroll
        for (int d = 0; d < 8; ++d) s2 += qd[d] * Bk[hb + d];
        A0 = a[0]; A1 = a[1]; A2 = a[2]; A3 = a[3]; Bsv = s2 * rs8;
    }

    // stream own head's T-slice: t = l + 32*i  (R6 loop: 52 VGPR, no spill)
    const float4*   lcp = (const float4*)local_coords + (size_t)n * 1024 + l;
    const uint32_t* mp  = (const uint32_t*)maskp +
                          (m4 ? ((size_t)n * 1024 + l)
                              : ((size_t)n * 256 + (l >> 2)));

    float p0 = 0.f, p1 = 0.f, p2 = 0.f, p3 = 0.f;
    float p4 = 0.f, p5 = 0.f, p6 = 0.f, p7 = 0.f;
    float s0 = 0.f;

    #pragma unroll 2
    for (int i = 0; i < 32; ++i) {
        const float4   lc = lcp[i * 32];
        const uint32_t mw = mp[i * mstep];
        const bool keep = ((mw >> msh) & mmsk) != 0u;
        const float v = Bsv + lc.x * A0 + lc.y * A1 + lc.z * A2 + lc.w * A3;
        const float e = keep ? __expf(v) : 0.f;   // |v| bounded by construction: no overflow
        s0 += e;
        const uint4 w = vq[bg + (i << 6)];
        p0 += e * bflo(w.x); p1 += e * bfhi(w.x);
        p2 += e * bflo(w.y); p3 += e * bfhi(w.y);
        p4 += e * bflo(w.z); p5 += e * bfhi(w.z);
        p6 += e * bflo(w.w); p7 += e * bfhi(w.w);
    }

    // head-total sum across the half-wave
    #pragma unroll
    for (int s = 16; s; s >>= 1) s0 += __shfl_xor(s0, s, 64);

    // all-masked fallback: softmax of constant row = uniform weights
    if (s0 == 0.0f) {
        #pragma unroll 2
        for (int i = 0; i < 32; ++i) {
            const uint4 w = vq[bg + (i << 6)];
            p0 += bflo(w.x); p1 += bfhi(w.x);
            p2 += bflo(w.y); p3 += bfhi(w.y);
            p4 += bflo(w.z); p5 += bfhi(w.z);
            p6 += bflo(w.w); p7 += bfhi(w.w);
        }
        s0 = 1024.0f;
    }

    // split butterfly within half-wave: lane ends with elem (lane>>2)&7
    {
        const bool b = (lane & 16) != 0;
        const float n0 = (b ? p4 : p0) + __shfl_xor(b ? p0 : p4, 16, 64);
        const float n1 = (b ? p5 : p1) + __shfl_xor(b ? p1 : p5, 16, 64);
        const float n2 = (b ? p6 : p2) + __shfl_xor(b ? p2 : p6, 16, 64);
        const float n3 = (b ? p7 : p3) + __shfl_xor(b ? p3 : p7, 16, 64);
        p0 = n0; p1 = n1; p2 = n2; p3 = n3;
    }
    {
        const bool b = (lane & 8) != 0;
        const float n0 = (b ? p2 : p0) + __shfl_xor(b ? p0 : p2, 8, 64);
        const float n1 = (b ? p3 : p1) + __shfl_xor(b ? p1 : p3, 8, 64);
        p0 = n0; p1 = n1;
    }
    {
        const bool b = (lane & 4) != 0;
        p0 = (b ? p1 : p0) + __shfl_xor(b ? p0 : p1, 4, 64);
    }
    p0 += __shfl_xor(p0, 2, 64);
    p0 += __shfl_xor(p0, 1, 64);

    if ((lane & 3) == 0)
        ws[(size_t)n * 16 + hb + ((lane >> 2) & 7)] = p0 / s0;
}

// ---------------- phase 2: Wo/exp + tanh MLP ----------------
__global__ void attn_phase2(const float* __restrict__ coord1,
                            const float* __restrict__ coord2,
                            const float* __restrict__ ws,
                            const float* __restrict__ Wo, const float* __restrict__ Bo,
                            const float* __restrict__ W1, const float* __restrict__ B1,
                            const float* __restrict__ W2, const float* __restrict__ B2,
                            const float* __restrict__ Wt, const float* __restrict__ Bt,
                            float* __restrict__ out)
{
    const int lane = threadIdx.x & 63;
    const int wid  = threadIdx.x >> 6;
    const int n    = (blockIdx.x << 2) + wid;  // one row per wave

    const float4 c1 = *(const float4*)(coord1 + n * 4);
    const float4 c2 = *(const float4*)(coord2 + n * 4);
    const float  av = ws[(size_t)n * 16 + (lane & 15)];   // lane c<16 holds attn[c]

    // att[j] = exp(-(attn . Wo[:,j] + Bo[j])), j = lane&15
    float attv;
    {
        const int j = lane & 15;
        float acc = Bo[j];
        #pragma unroll
        for (int c = 0; c < 16; ++c)
            acc += __shfl(av, c, 64) * Wo[c * 16 + j];
        attv = __expf(-acc);
    }

    // layer 1: act1[lane] = tanh([c1,c2,att] . W1[:,lane] + B1[lane])
    float a1;
    {
        float acc = B1[lane];
        acc += c1.x * W1[0 * 64 + lane] + c1.y * W1[1 * 64 + lane]
             + c1.z * W1[2 * 64 + lane] + c1.w * W1[3 * 64 + lane];
        acc += c2.x * W1[4 * 64 + lane] + c2.y * W1[5 * 64 + lane]
             + c2.z * W1[6 * 64 + lane] + c2.w * W1[7 * 64 + lane];
        #pragma unroll
        for (int c = 0; c < 16; ++c)
            acc += __shfl(attv, c, 64) * W1[(8 + c) * 64 + lane];
        a1 = ftanh(acc);
    }

    // layer 2: act2[lane] = tanh(act1 . W2[:,lane] + B2[lane])
    float a2;
    {
        float acc = B2[lane];
        #pragma unroll
        for (int c = 0; c < 64; ++c)
            acc += __shfl(a1, c, 64) * W2[c * 64 + lane];
        a2 = ftanh(acc);
    }

    // layer 3: out[lane&31] = tanh(act2 . Wt[:,lane&31] + Bt[lane&31])
    {
        const int j = lane & 31;
        float acc = Bt[j];
        #pragma unroll
        for (int c = 0; c < 64; ++c)
            acc += __shfl(a2, c, 64) * Wt[c * 32 + j];
        if (lane < 32) out[(size_t)n * 32 + lane] = ftanh(acc);
    }
}

extern "C" void kernel_launch(void* const* d_in, const int* in_sizes, int n_in,
                              void* d_out, int out_size, void* d_ws, size_t ws_size,
                              hipStream_t stream) {
    (void)in_sizes; (void)n_in; (void)out_size; (void)ws_size;
    float* ws = (float*)d_ws;   // 8192*16 floats = 512 KB
    attn_phase1<<<1024, 512, 0, stream>>>(
        (const float*)d_in[0],  (const float*)d_in[2],
        (const float*)d_in[3],  d_in[4],
        (const float*)d_in[5],  (const float*)d_in[6],
        (const float*)d_in[7],  (const float*)d_in[8],
        (const float*)d_in[9],  (const float*)d_in[10],
        ws);
    attn_phase2<<<2048, 256, 0, stream>>>(
        (const float*)d_in[0],  (const float*)d_in[1],
        ws,
        (const float*)d_in[11], (const float*)d_in[12],
        (const float*)d_in[13], (const float*)d_in[14],
        (const float*)d_in[15], (const float*)d_in[16],
        (const float*)d_in[17], (const float*)d_in[18],
        (float*)d_out);
}

// Round 9
// 58.145 us; speedup vs baseline: 2.4937x; 1.4281x over previous
//
#include <hip/hip_runtime.h>
#include <cstdint>

// Problem constants: N=8192, T=1024, CD=4, H=2, KD=VD=8, DA=8, AOD=16, LAT=64, OUT=32.
//
// Established: allocator caps ~64 VGPR (spills beyond). R8: no spill at 48
// VGPR but latency-bound (VALUBusy 17%, eff. read ~2.2 TB/s). R9: halve the
// latency chains (16 iters, full-wave t coverage, both heads per lane) and
// halve loop VMEM (mask staged to LDS bytes once per row). Live set ~52.

__device__ __forceinline__ float bflo(uint32_t u) { return __uint_as_float(u << 16); }
__device__ __forceinline__ float bfhi(uint32_t u) { return __uint_as_float(u & 0xFFFF0000u); }
__device__ __forceinline__ uint32_t f2bf(float f) {
    uint32_t x = __float_as_uint(f);
    return (x + 0x7FFFu + ((x >> 16) & 1u)) >> 16;   // RNE
}
__device__ __forceinline__ float ftanh(float x) {
    float e = __expf(2.0f * x);
    return 1.0f - 2.0f / (e + 1.0f);   // stable for +-inf of e
}

// ---------------- phase 1: masked attention -> attn[n,16] ----------------
__global__ __launch_bounds__(512)
void attn_phase1(const float* __restrict__ coord1,
                 const float* __restrict__ att_coeff,
                 const float* __restrict__ local_coords,
                 const void*  __restrict__ maskp,
                 const float* __restrict__ Wq, const float* __restrict__ Bq,
                 const float* __restrict__ Wk, const float* __restrict__ Bk,
                 const float* __restrict__ Wv, const float* __restrict__ Bv,
                 float* __restrict__ ws)
{
    __shared__ uint4    vq[2048];        // v table, bf16x2 packed, swizzled (32 KB)
    __shared__ uint32_t mrow[8][256];    // per-wave mask row as bytes (8 KB)

    const int tid  = threadIdx.x;
    const int lane = tid & 63;
    const int wid  = tid >> 6;           // 0..7

    // mask element size: 4-byte (int/float 0/1) vs 1-byte (bool)
    uint4 mm = ((const uint4*)maskp)[tid];
    bool ok = (mm.x <= 1u || mm.x == 0x3F800000u) &&
              (mm.y <= 1u || mm.y == 0x3F800000u) &&
              (mm.z <= 1u || mm.z == 0x3F800000u) &&
              (mm.w <= 1u || mm.w == 0x3F800000u);
    const bool m4 = (__all(ok) != 0);

    // stage v = att_coeff @ Wv + Bv (bf16x2, XOR-swizzled); 2 t's per thread
    #pragma unroll
    for (int tt = 0; tt < 2; ++tt) {
        const int t = tid * 2 + tt;
        const float4 a0 = *(const float4*)(att_coeff + t * 8);
        const float4 a1 = *(const float4*)(att_coeff + t * 8 + 4);
        float vr[16];
        #pragma unroll
        for (int o = 0; o < 16; ++o) {
            vr[o] = Bv[o]
                + a0.x * Wv[o]      + a0.y * Wv[16 + o] + a0.z * Wv[32 + o] + a0.w * Wv[48 + o]
                + a1.x * Wv[64 + o] + a1.y * Wv[80 + o] + a1.z * Wv[96 + o] + a1.w * Wv[112 + o];
        }
        #pragma unroll
        for (int h = 0; h < 2; ++h) {
            const int g  = 2 * t + h;
            const int gs = (g & ~7) | ((g ^ (g >> 3)) & 7);
            uint4 pk;
            pk.x = f2bf(vr[h * 8 + 0]) | (f2bf(vr[h * 8 + 1]) << 16);
            pk.y = f2bf(vr[h * 8 + 2]) | (f2bf(vr[h * 8 + 3]) << 16);
            pk.z = f2bf(vr[h * 8 + 4]) | (f2bf(vr[h * 8 + 5]) << 16);
            pk.w = f2bf(vr[h * 8 + 6]) | (f2bf(vr[h * 8 + 7]) << 16);
            vq[gs] = pk;
        }
    }

    const int n = (blockIdx.x << 3) + wid;     // one row per wave

    // stage this row's mask into LDS as bytes (nonzero = keep)
    if (m4) {
        const uint4* wp = (const uint4*)((const uint32_t*)maskp + (size_t)n * 1024) + lane * 4;
        uint4 pk;
        uint32_t b[4];
        #pragma unroll
        for (int j = 0; j < 4; ++j) {
            const uint4 w = wp[j];
            b[j] = (w.x ? 1u : 0u) | ((w.y ? 1u : 0u) << 8) |
                   ((w.z ? 1u : 0u) << 16) | ((w.w ? 1u : 0u) << 24);
        }
        pk.x = b[0]; pk.y = b[1]; pk.z = b[2]; pk.w = b[3];
        *(uint4*)&mrow[wid][lane * 4] = pk;
    } else {
        const uint4 w = ((const uint4*)((const uint8_t*)maskp + (size_t)n * 1024))[lane];
        *(uint4*)&mrow[wid][lane * 4] = w;
    }
    __syncthreads();

    // v-table group base for t = lane (i adds 128 per step; low-3 swizzle i-invariant)
    const int g0 = 2 * lane;
    const int bg = (g0 & ~7) | ((g0 ^ (g0 >> 3)) & 7);   // head0: vq[bg+128i]; head1: ^1
    const float rs8 = 0.35355339059327373f;              // 1/sqrt(KD)

    // both heads' q -> folded A[2][4], Bs[2]
    float A[2][4], Bs[2];
    {
        const float4 c1 = *(const float4*)(coord1 + n * 4);
        float q[16];
        #pragma unroll
        for (int o = 0; o < 16; ++o)
            q[o] = Bq[o] + c1.x * Wq[o] + c1.y * Wq[16 + o] + c1.z * Wq[32 + o] + c1.w * Wq[48 + o];
        #pragma unroll
        for (int h = 0; h < 2; ++h) {
            #pragma unroll
            for (int c = 0; c < 4; ++c) {
                float s = 0.f;
                #pragma unroll
                for (int d = 0; d < 8; ++d) s += q[h * 8 + d] * Wk[c * 16 + h * 8 + d];
                A[h][c] = s * rs8;
            }
            float s2 = 0.f;
            #pragma unroll
            for (int d = 0; d < 8; ++d) s2 += q[h * 8 + d] * Bk[h * 8 + d];
            Bs[h] = s2 * rs8;
        }
    }

    // ---- stream T: t = lane + 64*i, 16 iterations, 1 VMEM load each ----
    const float4* lcp = (const float4*)local_coords + (size_t)n * 1024 + lane;
    const int  mword = lane >> 2;            // word in mrow (+16 per i)
    const int  msh   = (lane & 3) * 8;

    float p[16];
    #pragma unroll
    for (int k = 0; k < 16; ++k) p[k] = 0.f;
    float s0 = 0.f, s1 = 0.f;

    #pragma unroll 2
    for (int i = 0; i < 16; ++i) {
        const float4 lc = lcp[i * 64];
        const uint32_t mw = mrow[wid][mword + 16 * i];
        const bool keep = ((mw >> msh) & 0xFFu) != 0u;
        const float v0 = Bs[0] + lc.x * A[0][0] + lc.y * A[0][1] + lc.z * A[0][2] + lc.w * A[0][3];
        const float v1 = Bs[1] + lc.x * A[1][0] + lc.y * A[1][1] + lc.z * A[1][2] + lc.w * A[1][3];
        const float e0 = keep ? __expf(v0) : 0.f;   // |v| bounded: no overflow
        const float e1 = keep ? __expf(v1) : 0.f;
        s0 += e0; s1 += e1;
        const uint4 w0 = vq[(bg + (i << 7))];
        const uint4 w1 = vq[(bg + (i << 7)) ^ 1];
        p[0]  += e0 * bflo(w0.x); p[1]  += e0 * bfhi(w0.x);
        p[2]  += e0 * bflo(w0.y); p[3]  += e0 * bfhi(w0.y);
        p[4]  += e0 * bflo(w0.z); p[5]  += e0 * bfhi(w0.z);
        p[6]  += e0 * bflo(w0.w); p[7]  += e0 * bfhi(w0.w);
        p[8]  += e1 * bflo(w1.x); p[9]  += e1 * bfhi(w1.x);
        p[10] += e1 * bflo(w1.y); p[11] += e1 * bfhi(w1.y);
        p[12] += e1 * bflo(w1.z); p[13] += e1 * bfhi(w1.z);
        p[14] += e1 * bflo(w1.w); p[15] += e1 * bfhi(w1.w);
    }

    // full-wave sums
    #pragma unroll
    for (int s = 32; s; s >>= 1) {
        s0 += __shfl_xor(s0, s, 64);
        s1 += __shfl_xor(s1, s, 64);
    }

    // all-masked fallback: uniform weights (p is exactly 0 in that case)
    if (s0 == 0.0f) {
        #pragma unroll 2
        for (int i = 0; i < 16; ++i) {
            const uint4 w0 = vq[(bg + (i << 7))];
            const uint4 w1 = vq[(bg + (i << 7)) ^ 1];
            p[0]  += bflo(w0.x); p[1]  += bfhi(w0.x);
            p[2]  += bflo(w0.y); p[3]  += bfhi(w0.y);
            p[4]  += bflo(w0.z); p[5]  += bfhi(w0.z);
            p[6]  += bflo(w0.w); p[7]  += bfhi(w0.w);
            p[8]  += bflo(w1.x); p[9]  += bfhi(w1.x);
            p[10] += bflo(w1.y); p[11] += bfhi(w1.y);
            p[12] += bflo(w1.z); p[13] += bfhi(w1.z);
            p[14] += bflo(w1.w); p[15] += bfhi(w1.w);
        }
        s0 = 1024.0f; s1 = 1024.0f;
    }

    // split butterfly (R2-verified): lane 4c ends owning attn[c], c=lane>>2
    {
        const bool h5 = (lane & 32) != 0;
        #pragma unroll
        for (int k = 0; k < 8; ++k) {
            const float snd = h5 ? p[k] : p[k + 8];
            const float kp  = h5 ? p[k + 8] : p[k];
            p[k] = kp + __shfl_xor(snd, 32, 64);
        }
        const bool h4 = (lane & 16) != 0;
        #pragma unroll
        for (int k = 0; k < 4; ++k) {
            const float snd = h4 ? p[k] : p[k + 4];
            const float kp  = h4 ? p[k + 4] : p[k];
            p[k] = kp + __shfl_xor(snd, 16, 64);
        }
        const bool h3 = (lane & 8) != 0;
        #pragma unroll
        for (int k = 0; k < 2; ++k) {
            const float snd = h3 ? p[k] : p[k + 2];
            const float kp  = h3 ? p[k + 2] : p[k];
            p[k] = kp + __shfl_xor(snd, 8, 64);
        }
        const bool h2 = (lane & 4) != 0;
        {
            const float snd = h2 ? p[0] : p[1];
            const float kp  = h2 ? p[1] : p[0];
            p[0] = kp + __shfl_xor(snd, 4, 64);
        }
        p[0] += __shfl_xor(p[0], 2, 64);
        p[0] += __shfl_xor(p[0], 1, 64);
    }

    if ((lane & 3) == 0)
        ws[(size_t)n * 16 + (lane >> 2)] = p[0] / (lane >= 32 ? s1 : s0);
}

// ---------------- phase 2: Wo/exp + tanh MLP ----------------
__global__ void attn_phase2(const float* __restrict__ coord1,
                            const float* __restrict__ coord2,
                            const float* __restrict__ ws,
                            const float* __restrict__ Wo, const float* __restrict__ Bo,
                            const float* __restrict__ W1, const float* __restrict__ B1,
                            const float* __restrict__ W2, const float* __restrict__ B2,
                            const float* __restrict__ Wt, const float* __restrict__ Bt,
                            float* __restrict__ out)
{
    const int lane = threadIdx.x & 63;
    const int wid  = threadIdx.x >> 6;
    const int n    = (blockIdx.x << 2) + wid;  // one row per wave

    const float4 c1 = *(const float4*)(coord1 + n * 4);
    const float4 c2 = *(const float4*)(coord2 + n * 4);
    const float  av = ws[(size_t)n * 16 + (lane & 15)];   // lane c<16 holds attn[c]

    // att[j] = exp(-(attn . Wo[:,j] + Bo[j])), j = lane&15
    float attv;
    {
        const int j = lane & 15;
        float acc = Bo[j];
        #pragma unroll
        for (int c = 0; c < 16; ++c)
            acc += __shfl(av, c, 64) * Wo[c * 16 + j];
        attv = __expf(-acc);
    }

    // layer 1: act1[lane] = tanh([c1,c2,att] . W1[:,lane] + B1[lane])
    float a1;
    {
        float acc = B1[lane];
        acc += c1.x * W1[0 * 64 + lane] + c1.y * W1[1 * 64 + lane]
             + c1.z * W1[2 * 64 + lane] + c1.w * W1[3 * 64 + lane];
        acc += c2.x * W1[4 * 64 + lane] + c2.y * W1[5 * 64 + lane]
             + c2.z * W1[6 * 64 + lane] + c2.w * W1[7 * 64 + lane];
        #pragma unroll
        for (int c = 0; c < 16; ++c)
            acc += __shfl(attv, c, 64) * W1[(8 + c) * 64 + lane];
        a1 = ftanh(acc);
    }

    // layer 2: act2[lane] = tanh(act1 . W2[:,lane] + B2[lane])
    float a2;
    {
        float acc = B2[lane];
        #pragma unroll
        for (int c = 0; c < 64; ++c)
            acc += __shfl(a1, c, 64) * W2[c * 64 + lane];
        a2 = ftanh(acc);
    }

    // layer 3: out[lane&31] = tanh(act2 . Wt[:,lane&31] + Bt[lane&31])
    {
        const int j = lane & 31;
        float acc = Bt[j];
        #pragma unroll
        for (int c = 0; c < 64; ++c)
            acc += __shfl(a2, c, 64) * Wt[c * 32 + j];
        if (lane < 32) out[(size_t)n * 32 + lane] = ftanh(acc);
    }
}

extern "C" void kernel_launch(void* const* d_in, const int* in_sizes, int n_in,
                              void* d_out, int out_size, void* d_ws, size_t ws_size,
                              hipStream_t stream) {
    (void)in_sizes; (void)n_in; (void)out_size; (void)ws_size;
    float* ws = (float*)d_ws;   // 8192*16 floats = 512 KB
    attn_phase1<<<1024, 512, 0, stream>>>(
        (const float*)d_in[0],  (const float*)d_in[2],
        (const float*)d_in[3],  d_in[4],
        (const float*)d_in[5],  (const float*)d_in[6],
        (const float*)d_in[7],  (const float*)d_in[8],
        (const float*)d_in[9],  (const float*)d_in[10],
        ws);
    attn_phase2<<<2048, 256, 0, stream>>>(
        (const float*)d_in[0],  (const float*)d_in[1],
        ws,
        (const float*)d_in[11], (const float*)d_in[12],
        (const float*)d_in[13], (const float*)d_in[14],
        (const float*)d_in[15], (const float*)d_in[16],
        (const float*)d_in[17], (const float*)d_in[18],
        (float*)d_out);
}